// Round 22
// baseline (121.557 us; speedup 1.0000x reference)
//
#include <hip/hip_runtime.h>
#include <hip/hip_bf16.h>

#define TEMP_INV (1.0f / 0.07f)
#define LOG2E 1.4426950408889634f
#define LN2 0.6931471805599453f
#define CFIX 21.0f

typedef __attribute__((ext_vector_type(4))) float f32x4;

// Fr layout: [kb 0..31][rb 0..NN/16-1][512B frag]; frag byte (hi*16+lo)*8+o =
// fp8(F[rb*16+lo][kb*32+hi*8+o]).  One 512B frag = one MFMA operand for a
// whole wave (lane-contiguous dwordx2). Proven absmax-0 in R18/R21.

// ---------------- Kernel 1: norms + cross + fp8 frag-layout via LDS transpose
// One block per 16-row group (b = 0..B/16-1): a-rows b*16+lo  -> rb = b,
// p-rows B+b*16+lo -> rb = B/16 + b. 256 threads.
// LDS row stride S=1048B: phase-2 b32 writes ~2-way (free), phase-3 b64
// transposed reads start-bank (6*lo+2*hi)%32 -> each even bank exactly 4x
// = the 512B/4-pass floor (conflict-free).
#define LQS 1048
__global__ __launch_bounds__(256) void norm_kernel(
    const float* __restrict__ A, const float* __restrict__ P,
    unsigned char* __restrict__ Fr, float* __restrict__ cross,
    float* __restrict__ lsum, int B, int D) {
  __shared__ unsigned char lq[32 * LQS];  // [32 rows][1024 fp8 + pad]
  __shared__ float nrm[16][2];
  const int b = blockIdx.x;
  const int t = threadIdx.x;
  {
    const int zi = b * 256 + t;
    if (zi < 2 * B) lsum[zi] = 0.f;
  }
  const int lo16 = t >> 4, sub = t & 15;
  const int ga = b * 16 + lo16;            // a-row
  const float4* a4 = reinterpret_cast<const float4*>(A + (size_t)ga * D);
  const float4* p4 = reinterpret_cast<const float4*>(P + (size_t)ga * D);
  const int n4 = D >> 2;  // 256

  // ---- pass 1: norms + cross (16 threads per row-pair) ----
  float sa = 0.f, sp = 0.f, sx = 0.f;
  for (int i = sub; i < n4; i += 16) {
    float4 av = a4[i], pv = p4[i];
    sa += av.x * av.x + av.y * av.y + av.z * av.z + av.w * av.w;
    sp += pv.x * pv.x + pv.y * pv.y + pv.z * pv.z + pv.w * pv.w;
    sx += av.x * pv.x + av.y * pv.y + av.z * pv.z + av.w * pv.w;
  }
#pragma unroll
  for (int off = 8; off; off >>= 1) {
    sa += __shfl_xor(sa, off);
    sp += __shfl_xor(sp, off);
    sx += __shfl_xor(sx, off);
  }
  if (sub == 0) {
    const float ian = rsqrtf(sa), ipn = rsqrtf(sp);
    nrm[lo16][0] = ian;
    nrm[lo16][1] = ipn;
    cross[ga] = sx * ian * ipn;
  }
  __syncthreads();

  // ---- pass 2: quantize (x16) into LDS rows (a: lo16, p: 16+lo16) ----
  const float ia = nrm[lo16][0] * 16.f, ip = nrm[lo16][1] * 16.f;
  unsigned char* la = &lq[lo16 * LQS];
  unsigned char* lp = &lq[(16 + lo16) * LQS];
  for (int i = sub; i < n4; i += 16) {
    float4 av = a4[i], pv = p4[i];
    int qa = 0, qp = 0;
    qa = __builtin_amdgcn_cvt_pk_fp8_f32(av.x * ia, av.y * ia, qa, false);
    qa = __builtin_amdgcn_cvt_pk_fp8_f32(av.z * ia, av.w * ia, qa, true);
    qp = __builtin_amdgcn_cvt_pk_fp8_f32(pv.x * ip, pv.y * ip, qp, false);
    qp = __builtin_amdgcn_cvt_pk_fp8_f32(pv.z * ip, pv.w * ip, qp, true);
    *reinterpret_cast<int*>(la + i * 4) = qa;
    *reinterpret_cast<int*>(lp + i * 4) = qp;
  }
  __syncthreads();

  // ---- pass 3: transposed COALESCED frag writes (64 frags, 4/step) ----
  const int pos = t & 63, wv = t >> 6;
  const int flo = pos & 15, fhi = pos >> 4;
  const size_t KBSTR = (size_t)((2 * B) >> 4) * 512;
#pragma unroll
  for (int s = 0; s < 16; ++s) {
    const int f = s * 4 + wv;          // 0..63
    const int rbsel = f >> 5, kb = f & 31;
    const int rb = (rbsel == 0) ? b : ((B >> 4) + b);
    const long v = *reinterpret_cast<const long*>(
        &lq[(rbsel * 16 + flo) * LQS + kb * 32 + fhi * 8]);
    *reinterpret_cast<long*>(Fr + (size_t)kb * KBSTR + (size_t)rb * 512 +
                             pos * 8) = v;
  }
}

// ---------------- Kernel 2: triangular fused Gram — reg-direct, 4-deep -------
// R21 architecture (97.6us, zero spill) + 4-stage named-register pipeline
// (rule #20-safe: static rotation, no runtime indexing). While stage kb
// computes, kb+1..kb+3 are in flight -> issue-to-use distance ~3x156cy covers
// L2 latency (R21 was depth-1 -> latency-bound at 28% MfmaUtil).
// 128x128 triangle tiles (2080 = 8*260), FULL K=1024, 4 waves (2x2 x 64x64).
// No LDS, no barriers: waves desync freely (the m114 overlap).
__global__ __launch_bounds__(256) void gram_kernel(
    const unsigned char* __restrict__ Fr, float* __restrict__ lsum, int NN,
    int D) {
  const int nrb = NN >> 7;               // 64 row-panels of 128
  const int ntri = nrb * (nrb + 1) / 2;  // 2080
  int lin = blockIdx.x;
  lin = (lin & 7) * (ntri >> 3) + (lin >> 3);  // XCD swizzle (2080 = 8*260)
  int by = (int)((sqrtf(8.f * (float)lin + 1.f) - 1.f) * 0.5f);
  while ((by + 1) * (by + 2) / 2 <= lin) ++by;
  while (by * (by + 1) / 2 > lin) --by;
  const int bx = lin - by * (by + 1) / 2;  // bx <= by
  const int r0 = bx * 128;  // i rows (B operand, N side)
  const int c0 = by * 128;  // j rows (A operand, M side)
  const bool diag = (bx == by);

  const int t = threadIdx.x;
  const int lane = t & 63, w = t >> 6;  // 4 waves
  const int lo = lane & 15, hi = lane >> 4;
  const int wr = w >> 1, wn = w & 1;  // wr: j-64 half, wn: i-64 half

  const size_t KBSTR = (size_t)(NN >> 4) * 512;  // bytes per kb block
  const unsigned char* pA =
      Fr + (size_t)((c0 >> 4) + wr * 4) * 512 + (size_t)lane * 8;
  const unsigned char* pB =
      Fr + (size_t)((r0 >> 4) + wn * 4) * 512 + (size_t)lane * 8;

  f32x4 acc[4][4];
#pragma unroll
  for (int a = 0; a < 4; ++a)
#pragma unroll
    for (int bb = 0; bb < 4; ++bb) acc[a][bb] = (f32x4){0.f, 0.f, 0.f, 0.f};

#define LOADST(ar, br, KB)                                        \
  do {                                                            \
    const size_t o_ = (size_t)(KB)*KBSTR;                         \
    _Pragma("unroll") for (int q = 0; q < 4; ++q) {               \
      ar[q] = *(const long*)(pA + o_ + q * 512);                  \
      br[q] = *(const long*)(pB + o_ + q * 512);                  \
    }                                                             \
  } while (0)

#define MFMAS(ar, br)                                             \
  do {                                                            \
    __builtin_amdgcn_s_setprio(1);                                \
    _Pragma("unroll") for (int mf = 0; mf < 4; ++mf)              \
      _Pragma("unroll") for (int nf = 0; nf < 4; ++nf)            \
          acc[mf][nf] = __builtin_amdgcn_mfma_f32_16x16x32_fp8_fp8( \
              ar[mf], br[nf], acc[mf][nf], 0, 0, 0);              \
    __builtin_amdgcn_s_setprio(0);                                \
  } while (0)

  long a0[4], b0[4], a1[4], b1[4], a2[4], b2[4], a3[4], b3[4];
  LOADST(a0, b0, 0);
  LOADST(a1, b1, 1);
  LOADST(a2, b2, 2);

#pragma unroll 1
  for (int kb = 0; kb < 32; kb += 4) {
    const int k3 = (kb + 3 < 32) ? kb + 3 : 31;
    const int k4 = (kb + 4 < 32) ? kb + 4 : 31;
    const int k5 = (kb + 5 < 32) ? kb + 5 : 31;
    const int k6 = (kb + 6 < 32) ? kb + 6 : 31;
    LOADST(a3, b3, k3);
    MFMAS(a0, b0);
    LOADST(a0, b0, k4);
    MFMAS(a1, b1);
    LOADST(a1, b1, k5);
    MFMAS(a2, b2);
    LOADST(a2, b2, k6);
    MFMAS(a3, b3);
  }

  // ---- dual-side epilogue (R16-R21-proven 64x64 wave-tile mapping) ----
  // acc[mf][nf][rg]: j = c0 + wr*64 + mf*16 + hi*4 + rg
  //                  i = r0 + wn*64 + nf*16 + lo
  const float scl = LOG2E * TEMP_INV / 256.f;  // descale x16*x16
  float s_i[4] = {0.f, 0.f, 0.f, 0.f};
  float s_j[16];
#pragma unroll
  for (int q = 0; q < 16; ++q) s_j[q] = 0.f;
  {
    const int dgb = (r0 + wn * 64) - (c0 + wr * 64);
#pragma unroll
    for (int nf = 0; nf < 4; ++nf) {
      const int dg = dgb + nf * 16 + lo;
#pragma unroll
      for (int mf = 0; mf < 4; ++mf)
#pragma unroll
        for (int rg = 0; rg < 4; ++rg) {
          const int jloc = mf * 16 + hi * 4 + rg;
          float e = exp2f(acc[mf][nf][rg] * scl - CFIX);
          if (diag && dg == jloc) e = 0.f;
          s_i[nf] += e;
          s_j[mf * 4 + rg] += e;
        }
    }
  }
#pragma unroll
  for (int nf = 0; nf < 4; ++nf) {
    float v = s_i[nf];
    v += __shfl_xor(v, 16);
    v += __shfl_xor(v, 32);
    if (hi == 0) atomicAdd(&lsum[r0 + wn * 64 + nf * 16 + lo], v);
  }
  if (!diag) {
#pragma unroll
    for (int q = 0; q < 16; ++q) {
      float v = s_j[q];
      v += __shfl_xor(v, 1);
      v += __shfl_xor(v, 2);
      v += __shfl_xor(v, 4);
      v += __shfl_xor(v, 8);
      if (lo == 0)
        atomicAdd(&lsum[c0 + wr * 64 + (q >> 2) * 16 + hi * 4 + (q & 3)], v);
    }
  }
#undef LOADST
#undef MFMAS
}

// ---------------- Kernel 3: merged finalize (single block, R20-proven) -------
__global__ __launch_bounds__(1024) void finalize_kernel(
    const float* __restrict__ lsum, const float* __restrict__ cross,
    const int* __restrict__ labels, float* __restrict__ out, int B) {
  const int NN = 2 * B;
  const int t = threadIdx.x;
  float sum = 0.f, cnt = 0.f;
  for (int i = t; i < NN; i += 1024) {
    const float lse = LN2 * (CFIX + log2f(lsum[i]));
    const float lab = (float)labels[i % B];
    sum += (lse - cross[i % B] * TEMP_INV) * lab;
    cnt += lab;
  }
#pragma unroll
  for (int off = 32; off; off >>= 1) {
    sum += __shfl_down(sum, off);
    cnt += __shfl_down(cnt, off);
  }
  __shared__ float rs[16], rc[16];
  const int wid = t >> 6, lane = t & 63;
  if (lane == 0) { rs[wid] = sum; rc[wid] = cnt; }
  __syncthreads();
  if (t == 0) {
    float S = 0.f, C = 0.f;
    for (int q = 0; q < 16; ++q) { S += rs[q]; C += rc[q]; }
    out[0] = (C > 0.f) ? S / C : 0.f;
  }
}

extern "C" void kernel_launch(void* const* d_in, const int* in_sizes, int n_in,
                              void* d_out, int out_size, void* d_ws, size_t ws_size,
                              hipStream_t stream) {
  const float* A = (const float*)d_in[0];
  const float* P = (const float*)d_in[1];
  const int* labels = (const int*)d_in[2];
  float* out = (float*)d_out;
  const int B = in_sizes[2];
  const int D = in_sizes[0] / B;
  const int NN = 2 * B;

  char* ws = (char*)d_ws;
  unsigned char* Fr = (unsigned char*)ws;
  size_t off = (size_t)NN * D;  // fp8 fragment-layout copy
  off = (off + 255) & ~(size_t)255;
  float* cross = (float*)(ws + off);
  off += (size_t)B * sizeof(float);
  off = (off + 255) & ~(size_t)255;
  float* lsum = (float*)(ws + off);

  norm_kernel<<<B / 16, 256, 0, stream>>>(A, P, Fr, cross, lsum, B, D);
  const int nrb = NN >> 7;               // 64 row-panels of 128
  const int ntri = nrb * (nrb + 1) / 2;  // 2080 triangle tiles
  gram_kernel<<<ntri, 256, 0, stream>>>(Fr, lsum, NN, D);
  finalize_kernel<<<1, 1024, 0, stream>>>(lsum, cross, labels, out, B);
}